// Round 17
// baseline (92.526 us; speedup 1.0000x reference)
//
#include <hip/hip_runtime.h>

typedef unsigned short ushort_t;
typedef __bf16 bf16x8 __attribute__((ext_vector_type(8)));
typedef float  f32x4  __attribute__((ext_vector_type(4)));

#define MFMA16(a,b,c) __builtin_amdgcn_mfma_f32_16x16x32_bf16((a),(b),(c),0,0,0)

__device__ __forceinline__ ushort_t f2bf(float f) {
    union { float f; unsigned u; } x; x.f = f;
    unsigned r = (x.u + 0x7fffu + ((x.u >> 16) & 1u)) >> 16;
    return (ushort_t)r;
}

__device__ __forceinline__ void gload16(const ushort_t* g, char* l) {
    __builtin_amdgcn_global_load_lds(
        (const __attribute__((address_space(1))) unsigned*)g,
        (__attribute__((address_space(3))) unsigned*)l, 16, 0, 0);
}

// ---------------- all casts in one launch ----------------
__global__ void cast_all(const float* __restrict__ x,
                         const float* __restrict__ Wq, const float* __restrict__ Wk,
                         const float* __restrict__ Wv, const float* __restrict__ Wo,
                         ushort_t* __restrict__ xbf, ushort_t* __restrict__ wqkv,
                         ushort_t* __restrict__ wob) {
    int i = blockIdx.x * 256 + threadIdx.x;
    float4 v;
    if (i < 1048576) {
        v = ((const float4*)x)[i];
        ushort4 o;
        o.x = f2bf(v.x); o.y = f2bf(v.y); o.z = f2bf(v.z); o.w = f2bf(v.w);
        ((ushort4*)xbf)[i] = o;
    } else {
        int j = i - 1048576;
        int r = j >> 18, jj = j & 0x3ffff;
        const float* src = (r == 0) ? Wq : (r == 1) ? Wk : (r == 2) ? Wv : Wo;
        v = ((const float4*)src)[jj];
        ushort4 o;
        o.x = f2bf(v.x); o.y = f2bf(v.y); o.z = f2bf(v.z); o.w = f2bf(v.w);
        if (r < 3) ((ushort4*)wqkv)[(size_t)r*262144 + jj] = o;
        else       ((ushort4*)wob)[jj] = o;
    }
}

// ---------------- QKV GEMM (r13 champion + T1 XCD swizzle) --------------------
// 128x128, BK=64, 2-barrier (both dbuf variants measured worse: r11, r14).
// Grid 768 1D, bijective XCD remap: each XCD gets 96 contiguous tiles = 3
// B-panels x all 32 m-tiles -> Wqkv panels land in one L2 instead of eight.
__global__ void gemm_qkv(const ushort_t* __restrict__ A,
                         const ushort_t* __restrict__ Bw,
                         const float* __restrict__ b0, const float* __restrict__ b1,
                         const float* __restrict__ b2,
                         void* __restrict__ C0, void* __restrict__ C1,
                         void* __restrict__ C2)
{
    __shared__ __align__(16) char lds[32768];
    char* As = lds;
    char* Bs = lds + 16384;
    const int tid  = threadIdx.x;
    const int lane = tid & 63;
    const int wid  = tid >> 6;
    const int wrow = wid >> 1;
    const int wcol = wid & 1;
    const int l15  = lane & 15;
    const int lhi  = lane >> 4;
    const int swz = (blockIdx.x & 7)*96 + (blockIdx.x >> 3);   // 768 = 8 x 96
    const int m0 = (swz & 31) * 128;
    const int n0 = (swz >> 5) * 128;

    f32x4 acc[4][4] = {};

    #define STAGE(kb)                                                          \
        _Pragma("unroll")                                                      \
        for (int k = 0; k < 4; ++k) {                                          \
            int idx = k*256 + tid;                                             \
            int row = idx >> 3, s = idx & 7;                                   \
            int sc = s ^ (row & 7);                                            \
            gload16(A  + (size_t)(m0+row)*1024 + (kb) + sc*8, As + idx*16);    \
            gload16(Bw + (size_t)(n0+row)*1024 + (kb) + sc*8, Bs + idx*16);    \
        }

    STAGE(0)
    for (int kt = 0; kt < 16; ++kt) {
        __syncthreads();
        #pragma unroll
        for (int ks = 0; ks < 2; ++ks) {
            bf16x8 af[4], bfr[4];
            #pragma unroll
            for (int i = 0; i < 4; ++i) {
                int row = wrow*64 + i*16 + l15;
                int sl  = ks*4 + lhi;
                af[i] = *(const bf16x8*)(As + row*128 + ((sl ^ (row & 7)) << 4));
            }
            #pragma unroll
            for (int j = 0; j < 4; ++j) {
                int row = wcol*64 + j*16 + l15;
                int sl  = ks*4 + lhi;
                bfr[j] = *(const bf16x8*)(Bs + row*128 + ((sl ^ (row & 7)) << 4));
            }
            #pragma unroll
            for (int i = 0; i < 4; ++i)
                #pragma unroll
                for (int j = 0; j < 4; ++j)
                    acc[i][j] = MFMA16(af[i], bfr[j], acc[i][j]);
        }
        __syncthreads();
        if (kt < 15) STAGE((kt+1)*64)
    }
    #undef STAGE

    const int reg  = n0 >> 10;                         // 0=Q, 1=K, 2=V
    const int nnw0 = (n0 & 1023) + wcol*64;
    const int h    = nnw0 >> 6;
    const int b    = (m0 + wrow*64) >> 11;
    const int s0w  = (m0 + wrow*64) & 2047;
    const size_t hh = (size_t)b*16 + h;
    const float* bp = (reg == 0) ? b0 : (reg == 1) ? b1 : b2;
    const float qsc = (reg == 0) ? 0.125f : 1.0f;      // fold 1/sqrt(Dk) into Q
    char* Cw = lds + wid*8192;

    if (reg == 2) {
        #pragma unroll
        for (int i = 0; i < 4; ++i)
            #pragma unroll
            for (int j = 0; j < 4; ++j)
                #pragma unroll
                for (int q = 0; q < 4; ++q) {
                    float v = acc[i][j][q] + bp[nnw0 + j*16 + l15];
                    int rowl = j*16 + l15;             // dk
                    int cb = (q*16 + i*4 + lhi) * 2;   // permuted s-local * 2B
                    *(__bf16*)(Cw + rowl*128 + (cb & 15) + ((((cb >> 4)) ^ (rowl & 7)) << 4)) = (__bf16)v;
                }
    } else {
        #pragma unroll
        for (int i = 0; i < 4; ++i)
            #pragma unroll
            for (int j = 0; j < 4; ++j)
                #pragma unroll
                for (int q = 0; q < 4; ++q) {
                    float v = (acc[i][j][q] + bp[nnw0 + j*16 + l15]) * qsc;
                    int rowl = i*16 + lhi*4 + q;       // s-local
                    int cb = (j*16 + l15) * 2;         // dk * 2B
                    *(__bf16*)(Cw + rowl*128 + (cb & 15) + ((((cb >> 4)) ^ (rowl & 7)) << 4)) = (__bf16)v;
                }
    }
    __syncthreads();

    const int rowr = lane >> 3;
    const int sl2  = lane & 7;
    #pragma unroll
    for (int p = 0; p < 8; ++p) {
        int row = p*8 + rowr;
        bf16x8 val = *(const bf16x8*)(Cw + row*128 + ((sl2 ^ (row & 7)) << 4));
        ushort_t* dst;
        if (reg == 0) {
            dst = (ushort_t*)C0 + (hh*2048 + s0w + row)*64 + sl2*8;
        } else if (reg == 1) {
            dst = (ushort_t*)C1 + ((hh*4 + (row & 3))*512 + (s0w >> 2) + (row >> 2))*64 + sl2*8;
        } else {
            dst = (ushort_t*)C2 + ((hh*4 + (sl2 >> 1))*64 + row)*512 + (s0w >> 2) + (sl2 & 1)*8;
        }
        *(bf16x8*)dst = val;
    }
}

// ---------------- O-proj GEMM (r13 champion + T1 XCD swizzle) -----------------
// Grid 512 1D: each XCD gets 64 contiguous tiles = exactly 1 B-panel.
__global__ void gemm_o(const ushort_t* __restrict__ A,
                       const ushort_t* __restrict__ Bw,
                       const float* __restrict__ b0,
                       float* __restrict__ C0)
{
    __shared__ __align__(16) char lds[24576];
    char* As = lds;              // 64 rows x 128B = 8KB
    char* Bs = lds + 8192;       // 128 rows x 128B = 16KB
    const int tid  = threadIdx.x;
    const int lane = tid & 63;
    const int wid  = tid >> 6;
    const int wrow = wid >> 1;
    const int wcol = wid & 1;
    const int l15  = lane & 15;
    const int lhi  = lane >> 4;
    const int swz = (blockIdx.x & 7)*64 + (blockIdx.x >> 3);   // 512 = 8 x 64
    const int m0 = (swz & 63) * 64;
    const int n0 = (swz >> 6) * 128;

    f32x4 acc[2][4] = {};

    #define STAGEO(kb)                                                         \
        _Pragma("unroll")                                                      \
        for (int k = 0; k < 2; ++k) {                                          \
            int idx = k*256 + tid;                                             \
            int row = idx >> 3, s = idx & 7;                                   \
            int sc = s ^ (row & 7);                                            \
            gload16(A + (size_t)(m0+row)*1024 + (kb) + sc*8, As + idx*16);     \
        }                                                                      \
        _Pragma("unroll")                                                      \
        for (int k = 0; k < 4; ++k) {                                          \
            int idx = k*256 + tid;                                             \
            int row = idx >> 3, s = idx & 7;                                   \
            int sc = s ^ (row & 7);                                            \
            gload16(Bw + (size_t)(n0+row)*1024 + (kb) + sc*8, Bs + idx*16);    \
        }

    STAGEO(0)
    for (int kt = 0; kt < 16; ++kt) {
        __syncthreads();
        #pragma unroll
        for (int ks = 0; ks < 2; ++ks) {
            bf16x8 af[2], bfr[4];
            #pragma unroll
            for (int i = 0; i < 2; ++i) {
                int row = wrow*32 + i*16 + l15;
                int sl  = ks*4 + lhi;
                af[i] = *(const bf16x8*)(As + row*128 + ((sl ^ (row & 7)) << 4));
            }
            #pragma unroll
            for (int j = 0; j < 4; ++j) {
                int row = wcol*64 + j*16 + l15;
                int sl  = ks*4 + lhi;
                bfr[j] = *(const bf16x8*)(Bs + row*128 + ((sl ^ (row & 7)) << 4));
            }
            #pragma unroll
            for (int i = 0; i < 2; ++i)
                #pragma unroll
                for (int j = 0; j < 4; ++j)
                    acc[i][j] = MFMA16(af[i], bfr[j], acc[i][j]);
        }
        __syncthreads();
        if (kt < 15) STAGEO((kt+1)*64)
    }
    #undef STAGEO

    #pragma unroll
    for (int i = 0; i < 2; ++i)
        #pragma unroll
        for (int j = 0; j < 4; ++j)
            #pragma unroll
            for (int q = 0; q < 4; ++q) {
                int gm = m0 + wrow*32 + i*16 + lhi*4 + q;
                int gn = n0 + wcol*64 + j*16 + l15;
                C0[(size_t)gm*1024 + gn] = acc[i][j][q] + b0[gn];
            }
}

// ---------------- sparse flash attention v8c (r15, unchanged) -----------------
__global__ __launch_bounds__(256, 2)
void sparse_attn8(const ushort_t* __restrict__ Qg,
                  const ushort_t* __restrict__ Kss,
                  const ushort_t* __restrict__ Vts,
                  ushort_t* __restrict__ attn)
{
    __shared__ __align__(16) char Klds[2][8192];
    __shared__ __align__(16) char Vlds[2][8192];
    __shared__ __align__(16) char Ps[8192];
    const int tid  = threadIdx.x;
    const int lane = tid & 63;
    const int w    = tid >> 6;
    const int l15  = lane & 15;
    const int lhi  = lane >> 4;
    const int id2  = (blockIdx.x & 7)*128 + (blockIdx.x >> 3);   // XCD: 4 heads each
    const int bh   = id2 >> 5;
    const int rem  = id2 & 31;
    const int r    = rem >> 3;      // residue
    const int g    = rem & 7;       // row-group
    char* Pw = Ps + w*2048;

    const ushort_t* Kst0 = Kss + (size_t)bh*4*512*64;
    const ushort_t* Vts0 = Vts + (size_t)bh*4*64*512;
    const ushort_t* Kst  = Kst0 + (size_t)r*512*64;
    const ushort_t* Vst  = Vts0 + (size_t)r*64*512;

    const int bl0 = (g > 0) ? 4*g - 1 : 0;
    const int bl1 = (g < 7) ? 4*g + 4 : 31;
    const int NT  = 8 + (bl1 - bl0 + 1);

    bf16x8 aq[2];
    {
        const ushort_t* qp = Qg + ((size_t)bh*2048 + r + 4*(g*64 + w*16 + l15))*64 + lhi*8;
        aq[0] = *(const bf16x8*)(qp);
        aq[1] = *(const bf16x8*)(qp + 32);
    }

    float tsum[4] = {0.f, 0.f, 0.f, 0.f};
    f32x4 oacc[4] = {};

    #define ASTAGE(t, b)                                                           \
        _Pragma("unroll")                                                          \
        for (int k = 0; k < 2; ++k) {                                              \
            int idx = k*256 + tid;                                                 \
            int row = idx >> 3, s = idx & 7;                                       \
            int sc = s ^ (row & 7);                                                \
            if ((t) < 8) {                                                         \
                gload16(Kst + (size_t)((t)*64 + row)*64 + sc*8, &Klds[b][idx*16]); \
                gload16(Vst + (size_t)row*512 + (t)*64 + sc*8, &Vlds[b][idx*16]);  \
            } else {                                                               \
                int bl = bl0 + (t) - 8;                                            \
                gload16(Kst0 + (size_t)((row>>4)*512 + bl*16 + (row&15))*64 + sc*8,\
                        &Klds[b][idx*16]);                                         \
                gload16(Vts0 + (size_t)((sc>>1)*64 + row)*512 + bl*16 + (sc&1)*8,  \
                        &Vlds[b][idx*16]);                                         \
            }                                                                      \
        }

    ASTAGE(0, 0)
    int cur = 0;
    for (int t = 0; t < NT; ++t) {
        __syncthreads();
        if (t + 1 < NT) ASTAGE(t + 1, cur ^ 1)
        f32x4 sacc[4] = {};
        __builtin_amdgcn_s_setprio(1);
        #pragma unroll
        for (int ks = 0; ks < 2; ++ks) {
            bf16x8 bk[4];
            #pragma unroll
            for (int n = 0; n < 4; ++n) {
                int row = n*16 + l15;
                int sl  = ks*4 + lhi;
                bk[n] = *(const bf16x8*)(&Klds[cur][row*128 + ((sl ^ (row & 7)) << 4)]);
            }
            #pragma unroll
            for (int n = 0; n < 4; ++n)
                sacc[n] = MFMA16(aq[ks], bk[n], sacc[n]);
        }
        __builtin_amdgcn_s_setprio(0);
        if (t < 8) {
            #pragma unroll
            for (int n = 0; n < 4; ++n) {
                int colb = (n*16 + l15) * 2;
                #pragma unroll
                for (int q = 0; q < 4; ++q) {
                    float p = __expf(sacc[n][q] - 16.f);   // Q pre-scaled by 0.125
                    tsum[q] += p;
                    int rowp = lhi*4 + q;
                    *(__bf16*)(Pw + rowp*128 + (colb ^ ((rowp & 7) << 4))) = (__bf16)p;
                }
            }
        } else {
            int bl = bl0 + t - 8;
            #pragma unroll
            for (int n = 0; n < 4; ++n) {
                int j = 4*(bl*16 + l15) + n;
                int colb = (n*16 + l15) * 2;
                bool nres = (n != r);
                #pragma unroll
                for (int q = 0; q < 4; ++q) {
                    int i = r + 4*(g*64 + w*16 + 4*lhi + q);
                    int d = j - i;
                    bool valid = nres && (d <= 32) && (d >= -32);
                    float sv = valid ? sacc[n][q] : -1e30f;
                    float p = __expf(sv - 16.f);
                    tsum[q] += p;
                    int rowp = lhi*4 + q;
                    *(__bf16*)(Pw + rowp*128 + (colb ^ ((rowp & 7) << 4))) = (__bf16)p;
                }
            }
        }
        __builtin_amdgcn_s_setprio(1);
        #pragma unroll
        for (int ks = 0; ks < 2; ++ks) {
            int sl = ks*4 + lhi;
            bf16x8 pf = *(const bf16x8*)(Pw + l15*128 + ((sl ^ (l15 & 7)) << 4));
            #pragma unroll
            for (int d = 0; d < 4; ++d) {
                int rowv = d*16 + l15;
                bf16x8 vf = *(const bf16x8*)(&Vlds[cur][rowv*128 + ((sl ^ (rowv & 7)) << 4)]);
                oacc[d] = MFMA16(pf, vf, oacc[d]);
            }
        }
        __builtin_amdgcn_s_setprio(0);
        cur ^= 1;
    }
    #undef ASTAGE

    const int b = bh >> 4, h = bh & 15;
    f32x4 invv;
    #pragma unroll
    for (int q = 0; q < 4; ++q) {
        float t = tsum[q];
        t += __shfl_xor(t, 1);
        t += __shfl_xor(t, 2);
        t += __shfl_xor(t, 4);
        t += __shfl_xor(t, 8);
        invv[q] = 1.f / t;
    }
    #pragma unroll
    for (int d = 0; d < 4; ++d) {
        f32x4 o = oacc[d] * invv;
        #pragma unroll
        for (int q = 0; q < 4; ++q) {
            int srow = r + 4*(g*64 + w*16 + 4*lhi + q);
            int gr = b*2048 + srow;
            int gc = h*64 + d*16 + l15;
            attn[(size_t)gr*1024 + gc] = f2bf(o[q]);
        }
    }
}

extern "C" void kernel_launch(void* const* d_in, const int* in_sizes, int n_in,
                              void* d_out, int out_size, void* d_ws, size_t ws_size,
                              hipStream_t stream)
{
    const float* x  = (const float*)d_in[0];
    const float* Wq = (const float*)d_in[1];
    const float* bq = (const float*)d_in[2];
    const float* Wk = (const float*)d_in[3];
    const float* bk = (const float*)d_in[4];
    const float* Wv = (const float*)d_in[5];
    const float* bv = (const float*)d_in[6];
    const float* Wo = (const float*)d_in[7];
    const float* bo = (const float*)d_in[8];

    char* ws = (char*)d_ws;
    ushort_t* xbf  = (ushort_t*)(ws);                        // 8 MB
    ushort_t* wqkv = (ushort_t*)(ws + ((size_t)8  << 20));   // 6 MB [3072][1024]
    ushort_t* wob  = (ushort_t*)(ws + ((size_t)14 << 20));   // 2 MB
    ushort_t* Qb   = (ushort_t*)(ws + ((size_t)16 << 20));   // 8 MB [BH,S,Dk] (x0.125)
    ushort_t* Kss  = (ushort_t*)(ws + ((size_t)24 << 20));   // 8 MB [BH,4,512,64]
    ushort_t* Vts  = (ushort_t*)(ws + ((size_t)32 << 20));   // 8 MB [BH,4,64,512]
    ushort_t* attn = (ushort_t*)(ws + ((size_t)40 << 20));   // 8 MB

    cast_all<<<8192, 256, 0, stream>>>(x, Wq, Wk, Wv, Wo, xbf, wqkv, wob);

    gemm_qkv<<<dim3(768), 256, 0, stream>>>(xbf, wqkv, bq, bk, bv,
                                            Qb, Kss, Vts);

    sparse_attn8<<<dim3(1024), 256, 0, stream>>>(Qb, Kss, Vts, attn);

    gemm_o<<<dim3(512), 256, 0, stream>>>(attn, wob, bo, (float*)d_out);
}

// Round 18
// 91.594 us; speedup vs baseline: 1.0102x; 1.0102x over previous
//
#include <hip/hip_runtime.h>

typedef unsigned short ushort_t;
typedef __bf16 bf16x8 __attribute__((ext_vector_type(8)));
typedef float  f32x4  __attribute__((ext_vector_type(4)));

#define MFMA16(a,b,c) __builtin_amdgcn_mfma_f32_16x16x32_bf16((a),(b),(c),0,0,0)

__device__ __forceinline__ ushort_t f2bf(float f) {
    union { float f; unsigned u; } x; x.f = f;
    unsigned r = (x.u + 0x7fffu + ((x.u >> 16) & 1u)) >> 16;
    return (ushort_t)r;
}

__device__ __forceinline__ void gload16(const ushort_t* g, char* l) {
    __builtin_amdgcn_global_load_lds(
        (const __attribute__((address_space(1))) unsigned*)g,
        (__attribute__((address_space(3))) unsigned*)l, 16, 0, 0);
}

// ---------------- all casts in one launch ----------------
__global__ void cast_all(const float* __restrict__ x,
                         const float* __restrict__ Wq, const float* __restrict__ Wk,
                         const float* __restrict__ Wv, const float* __restrict__ Wo,
                         ushort_t* __restrict__ xbf, ushort_t* __restrict__ wqkv,
                         ushort_t* __restrict__ wob) {
    int i = blockIdx.x * 256 + threadIdx.x;
    float4 v;
    if (i < 1048576) {
        v = ((const float4*)x)[i];
        ushort4 o;
        o.x = f2bf(v.x); o.y = f2bf(v.y); o.z = f2bf(v.z); o.w = f2bf(v.w);
        ((ushort4*)xbf)[i] = o;
    } else {
        int j = i - 1048576;
        int r = j >> 18, jj = j & 0x3ffff;
        const float* src = (r == 0) ? Wq : (r == 1) ? Wk : (r == 2) ? Wv : Wo;
        v = ((const float4*)src)[jj];
        ushort4 o;
        o.x = f2bf(v.x); o.y = f2bf(v.y); o.z = f2bf(v.z); o.w = f2bf(v.w);
        if (r < 3) ((ushort4*)wqkv)[(size_t)r*262144 + jj] = o;
        else       ((ushort4*)wob)[jj] = o;
    }
}

// ---------------- QKV GEMM (r13/r15 champion): 128x128, BK=64, 2-barrier ------
// Neighbors measured worse: BK=64 dbuf (r11 -30%), BK=32 dbuf (r14 -11%),
// T1 grid swizzle (r17, neutral-negative: panels already L3-fit, m160).
__global__ void gemm_qkv(const ushort_t* __restrict__ A,
                         const ushort_t* __restrict__ Bw,
                         const float* __restrict__ b0, const float* __restrict__ b1,
                         const float* __restrict__ b2,
                         void* __restrict__ C0, void* __restrict__ C1,
                         void* __restrict__ C2)
{
    __shared__ __align__(16) char lds[32768];
    char* As = lds;
    char* Bs = lds + 16384;
    const int tid  = threadIdx.x;
    const int lane = tid & 63;
    const int wid  = tid >> 6;
    const int wrow = wid >> 1;
    const int wcol = wid & 1;
    const int l15  = lane & 15;
    const int lhi  = lane >> 4;
    const int m0 = blockIdx.x * 128;
    const int n0 = blockIdx.y * 128;

    f32x4 acc[4][4] = {};

    #define STAGE(kb)                                                          \
        _Pragma("unroll")                                                      \
        for (int k = 0; k < 4; ++k) {                                          \
            int idx = k*256 + tid;                                             \
            int row = idx >> 3, s = idx & 7;                                   \
            int sc = s ^ (row & 7);                                            \
            gload16(A  + (size_t)(m0+row)*1024 + (kb) + sc*8, As + idx*16);    \
            gload16(Bw + (size_t)(n0+row)*1024 + (kb) + sc*8, Bs + idx*16);    \
        }

    STAGE(0)
    for (int kt = 0; kt < 16; ++kt) {
        __syncthreads();
        #pragma unroll
        for (int ks = 0; ks < 2; ++ks) {
            bf16x8 af[4], bfr[4];
            #pragma unroll
            for (int i = 0; i < 4; ++i) {
                int row = wrow*64 + i*16 + l15;
                int sl  = ks*4 + lhi;
                af[i] = *(const bf16x8*)(As + row*128 + ((sl ^ (row & 7)) << 4));
            }
            #pragma unroll
            for (int j = 0; j < 4; ++j) {
                int row = wcol*64 + j*16 + l15;
                int sl  = ks*4 + lhi;
                bfr[j] = *(const bf16x8*)(Bs + row*128 + ((sl ^ (row & 7)) << 4));
            }
            #pragma unroll
            for (int i = 0; i < 4; ++i)
                #pragma unroll
                for (int j = 0; j < 4; ++j)
                    acc[i][j] = MFMA16(af[i], bfr[j], acc[i][j]);
        }
        __syncthreads();
        if (kt < 15) STAGE((kt+1)*64)
    }
    #undef STAGE

    const int reg  = n0 >> 10;                         // 0=Q, 1=K, 2=V
    const int nnw0 = (n0 & 1023) + wcol*64;
    const int h    = nnw0 >> 6;
    const int b    = (m0 + wrow*64) >> 11;
    const int s0w  = (m0 + wrow*64) & 2047;
    const size_t hh = (size_t)b*16 + h;
    const float* bp = (reg == 0) ? b0 : (reg == 1) ? b1 : b2;
    const float qsc = (reg == 0) ? 0.125f : 1.0f;      // fold 1/sqrt(Dk) into Q
    char* Cw = lds + wid*8192;

    if (reg == 2) {
        #pragma unroll
        for (int i = 0; i < 4; ++i)
            #pragma unroll
            for (int j = 0; j < 4; ++j)
                #pragma unroll
                for (int q = 0; q < 4; ++q) {
                    float v = acc[i][j][q] + bp[nnw0 + j*16 + l15];
                    int rowl = j*16 + l15;             // dk
                    int cb = (q*16 + i*4 + lhi) * 2;   // permuted s-local * 2B
                    *(__bf16*)(Cw + rowl*128 + (cb & 15) + ((((cb >> 4)) ^ (rowl & 7)) << 4)) = (__bf16)v;
                }
    } else {
        #pragma unroll
        for (int i = 0; i < 4; ++i)
            #pragma unroll
            for (int j = 0; j < 4; ++j)
                #pragma unroll
                for (int q = 0; q < 4; ++q) {
                    float v = (acc[i][j][q] + bp[nnw0 + j*16 + l15]) * qsc;
                    int rowl = i*16 + lhi*4 + q;       // s-local
                    int cb = (j*16 + l15) * 2;         // dk * 2B
                    *(__bf16*)(Cw + rowl*128 + (cb & 15) + ((((cb >> 4)) ^ (rowl & 7)) << 4)) = (__bf16)v;
                }
    }
    __syncthreads();

    const int rowr = lane >> 3;
    const int sl2  = lane & 7;
    #pragma unroll
    for (int p = 0; p < 8; ++p) {
        int row = p*8 + rowr;
        bf16x8 val = *(const bf16x8*)(Cw + row*128 + ((sl2 ^ (row & 7)) << 4));
        ushort_t* dst;
        if (reg == 0) {
            dst = (ushort_t*)C0 + (hh*2048 + s0w + row)*64 + sl2*8;
        } else if (reg == 1) {
            dst = (ushort_t*)C1 + ((hh*4 + (row & 3))*512 + (s0w >> 2) + (row >> 2))*64 + sl2*8;
        } else {
            dst = (ushort_t*)C2 + ((hh*4 + (sl2 >> 1))*64 + row)*512 + (s0w >> 2) + (sl2 & 1)*8;
        }
        *(bf16x8*)dst = val;
    }
}

// ---------------- O-proj GEMM (r13/r15 champion): 64x128 tile, grid 512 -------
__global__ void gemm_o(const ushort_t* __restrict__ A,
                       const ushort_t* __restrict__ Bw,
                       const float* __restrict__ b0,
                       float* __restrict__ C0)
{
    __shared__ __align__(16) char lds[24576];
    char* As = lds;              // 64 rows x 128B = 8KB
    char* Bs = lds + 8192;       // 128 rows x 128B = 16KB
    const int tid  = threadIdx.x;
    const int lane = tid & 63;
    const int wid  = tid >> 6;
    const int wrow = wid >> 1;
    const int wcol = wid & 1;
    const int l15  = lane & 15;
    const int lhi  = lane >> 4;
    const int m0 = blockIdx.x * 64;
    const int n0 = blockIdx.y * 128;

    f32x4 acc[2][4] = {};

    #define STAGEO(kb)                                                         \
        _Pragma("unroll")                                                      \
        for (int k = 0; k < 2; ++k) {                                          \
            int idx = k*256 + tid;                                             \
            int row = idx >> 3, s = idx & 7;                                   \
            int sc = s ^ (row & 7);                                            \
            gload16(A + (size_t)(m0+row)*1024 + (kb) + sc*8, As + idx*16);     \
        }                                                                      \
        _Pragma("unroll")                                                      \
        for (int k = 0; k < 4; ++k) {                                          \
            int idx = k*256 + tid;                                             \
            int row = idx >> 3, s = idx & 7;                                   \
            int sc = s ^ (row & 7);                                            \
            gload16(Bw + (size_t)(n0+row)*1024 + (kb) + sc*8, Bs + idx*16);    \
        }

    STAGEO(0)
    for (int kt = 0; kt < 16; ++kt) {
        __syncthreads();
        #pragma unroll
        for (int ks = 0; ks < 2; ++ks) {
            bf16x8 af[2], bfr[4];
            #pragma unroll
            for (int i = 0; i < 2; ++i) {
                int row = wrow*32 + i*16 + l15;
                int sl  = ks*4 + lhi;
                af[i] = *(const bf16x8*)(As + row*128 + ((sl ^ (row & 7)) << 4));
            }
            #pragma unroll
            for (int j = 0; j < 4; ++j) {
                int row = wcol*64 + j*16 + l15;
                int sl  = ks*4 + lhi;
                bfr[j] = *(const bf16x8*)(Bs + row*128 + ((sl ^ (row & 7)) << 4));
            }
            #pragma unroll
            for (int i = 0; i < 2; ++i)
                #pragma unroll
                for (int j = 0; j < 4; ++j)
                    acc[i][j] = MFMA16(af[i], bfr[j], acc[i][j]);
        }
        __syncthreads();
        if (kt < 15) STAGEO((kt+1)*64)
    }
    #undef STAGEO

    #pragma unroll
    for (int i = 0; i < 2; ++i)
        #pragma unroll
        for (int j = 0; j < 4; ++j)
            #pragma unroll
            for (int q = 0; q < 4; ++q) {
                int gm = m0 + wrow*32 + i*16 + lhi*4 + q;
                int gn = n0 + wcol*64 + j*16 + l15;
                C0[(size_t)gm*1024 + gn] = acc[i][j][q] + b0[gn];
            }
}

// ---------------- sparse flash attention v9: 4 WGs/CU ----------------
// (256,2) was a relic of the r8 spill era (reg-prefetch needed 256-VGPR
// budget). v8 is LDS-staged (~80-90 VGPR) -> (256,4) fits the 128-VGPR
// budget; LDS 40KB x 4 = 160KB exactly. Per-XCD working set UNCHANGED:
// XCD chunk = 128 WGs = 4 heads = 2MB Kss+Vts < 4MB L2; only TLP doubles.
__global__ __launch_bounds__(256, 4)
void sparse_attn9(const ushort_t* __restrict__ Qg,
                  const ushort_t* __restrict__ Kss,
                  const ushort_t* __restrict__ Vts,
                  ushort_t* __restrict__ attn)
{
    __shared__ __align__(16) char Klds[2][8192];
    __shared__ __align__(16) char Vlds[2][8192];
    __shared__ __align__(16) char Ps[8192];
    const int tid  = threadIdx.x;
    const int lane = tid & 63;
    const int w    = tid >> 6;
    const int l15  = lane & 15;
    const int lhi  = lane >> 4;
    const int id2  = (blockIdx.x & 7)*128 + (blockIdx.x >> 3);   // XCD: 4 heads each
    const int bh   = id2 >> 5;
    const int rem  = id2 & 31;
    const int r    = rem >> 3;      // residue
    const int g    = rem & 7;       // row-group
    char* Pw = Ps + w*2048;

    const ushort_t* Kst0 = Kss + (size_t)bh*4*512*64;
    const ushort_t* Vts0 = Vts + (size_t)bh*4*64*512;
    const ushort_t* Kst  = Kst0 + (size_t)r*512*64;
    const ushort_t* Vst  = Vts0 + (size_t)r*64*512;

    const int bl0 = (g > 0) ? 4*g - 1 : 0;
    const int bl1 = (g < 7) ? 4*g + 4 : 31;
    const int NT  = 8 + (bl1 - bl0 + 1);

    bf16x8 aq[2];
    {
        const ushort_t* qp = Qg + ((size_t)bh*2048 + r + 4*(g*64 + w*16 + l15))*64 + lhi*8;
        aq[0] = *(const bf16x8*)(qp);
        aq[1] = *(const bf16x8*)(qp + 32);
    }

    float tsum[4] = {0.f, 0.f, 0.f, 0.f};
    f32x4 oacc[4] = {};

    #define ASTAGE(t, b)                                                           \
        _Pragma("unroll")                                                          \
        for (int k = 0; k < 2; ++k) {                                              \
            int idx = k*256 + tid;                                                 \
            int row = idx >> 3, s = idx & 7;                                       \
            int sc = s ^ (row & 7);                                                \
            if ((t) < 8) {                                                         \
                gload16(Kst + (size_t)((t)*64 + row)*64 + sc*8, &Klds[b][idx*16]); \
                gload16(Vst + (size_t)row*512 + (t)*64 + sc*8, &Vlds[b][idx*16]);  \
            } else {                                                               \
                int bl = bl0 + (t) - 8;                                            \
                gload16(Kst0 + (size_t)((row>>4)*512 + bl*16 + (row&15))*64 + sc*8,\
                        &Klds[b][idx*16]);                                         \
                gload16(Vts0 + (size_t)((sc>>1)*64 + row)*512 + bl*16 + (sc&1)*8,  \
                        &Vlds[b][idx*16]);                                         \
            }                                                                      \
        }

    ASTAGE(0, 0)
    int cur = 0;
    for (int t = 0; t < NT; ++t) {
        __syncthreads();
        if (t + 1 < NT) ASTAGE(t + 1, cur ^ 1)
        f32x4 sacc[4] = {};
        __builtin_amdgcn_s_setprio(1);
        #pragma unroll
        for (int ks = 0; ks < 2; ++ks) {
            bf16x8 bk[4];
            #pragma unroll
            for (int n = 0; n < 4; ++n) {
                int row = n*16 + l15;
                int sl  = ks*4 + lhi;
                bk[n] = *(const bf16x8*)(&Klds[cur][row*128 + ((sl ^ (row & 7)) << 4)]);
            }
            #pragma unroll
            for (int n = 0; n < 4; ++n)
                sacc[n] = MFMA16(aq[ks], bk[n], sacc[n]);
        }
        __builtin_amdgcn_s_setprio(0);
        if (t < 8) {
            #pragma unroll
            for (int n = 0; n < 4; ++n) {
                int colb = (n*16 + l15) * 2;
                #pragma unroll
                for (int q = 0; q < 4; ++q) {
                    float p = __expf(sacc[n][q] - 16.f);   // Q pre-scaled by 0.125
                    tsum[q] += p;
                    int rowp = lhi*4 + q;
                    *(__bf16*)(Pw + rowp*128 + (colb ^ ((rowp & 7) << 4))) = (__bf16)p;
                }
            }
        } else {
            int bl = bl0 + t - 8;
            #pragma unroll
            for (int n = 0; n < 4; ++n) {
                int j = 4*(bl*16 + l15) + n;
                int colb = (n*16 + l15) * 2;
                bool nres = (n != r);
                #pragma unroll
                for (int q = 0; q < 4; ++q) {
                    int i = r + 4*(g*64 + w*16 + 4*lhi + q);
                    int d = j - i;
                    bool valid = nres && (d <= 32) && (d >= -32);
                    float sv = valid ? sacc[n][q] : -1e30f;
                    float p = __expf(sv - 16.f);
                    tsum[q] += p;
                    int rowp = lhi*4 + q;
                    *(__bf16*)(Pw + rowp*128 + (colb ^ ((rowp & 7) << 4))) = (__bf16)p;
                }
            }
        }
        __builtin_amdgcn_s_setprio(1);
        #pragma unroll
        for (int ks = 0; ks < 2; ++ks) {
            int sl = ks*4 + lhi;
            bf16x8 pf = *(const bf16x8*)(Pw + l15*128 + ((sl ^ (l15 & 7)) << 4));
            #pragma unroll
            for (int d = 0; d < 4; ++d) {
                int rowv = d*16 + l15;
                bf16x8 vf = *(const bf16x8*)(&Vlds[cur][rowv*128 + ((sl ^ (rowv & 7)) << 4)]);
                oacc[d] = MFMA16(pf, vf, oacc[d]);
            }
        }
        __builtin_amdgcn_s_setprio(0);
        cur ^= 1;
    }
    #undef ASTAGE

    const int b = bh >> 4, h = bh & 15;
    f32x4 invv;
    #pragma unroll
    for (int q = 0; q < 4; ++q) {
        float t = tsum[q];
        t += __shfl_xor(t, 1);
        t += __shfl_xor(t, 2);
        t += __shfl_xor(t, 4);
        t += __shfl_xor(t, 8);
        invv[q] = 1.f / t;
    }
    #pragma unroll
    for (int d = 0; d < 4; ++d) {
        f32x4 o = oacc[d] * invv;
        #pragma unroll
        for (int q = 0; q < 4; ++q) {
            int srow = r + 4*(g*64 + w*16 + 4*lhi + q);
            int gr = b*2048 + srow;
            int gc = h*64 + d*16 + l15;
            attn[(size_t)gr*1024 + gc] = f2bf(o[q]);
        }
    }
}

extern "C" void kernel_launch(void* const* d_in, const int* in_sizes, int n_in,
                              void* d_out, int out_size, void* d_ws, size_t ws_size,
                              hipStream_t stream)
{
    const float* x  = (const float*)d_in[0];
    const float* Wq = (const float*)d_in[1];
    const float* bq = (const float*)d_in[2];
    const float* Wk = (const float*)d_in[3];
    const float* bk = (const float*)d_in[4];
    const float* Wv = (const float*)d_in[5];
    const float* bv = (const float*)d_in[6];
    const float* Wo = (const float*)d_in[7];
    const float* bo = (const float*)d_in[8];

    char* ws = (char*)d_ws;
    ushort_t* xbf  = (ushort_t*)(ws);                        // 8 MB
    ushort_t* wqkv = (ushort_t*)(ws + ((size_t)8  << 20));   // 6 MB [3072][1024]
    ushort_t* wob  = (ushort_t*)(ws + ((size_t)14 << 20));   // 2 MB
    ushort_t* Qb   = (ushort_t*)(ws + ((size_t)16 << 20));   // 8 MB [BH,S,Dk] (x0.125)
    ushort_t* Kss  = (ushort_t*)(ws + ((size_t)24 << 20));   // 8 MB [BH,4,512,64]
    ushort_t* Vts  = (ushort_t*)(ws + ((size_t)32 << 20));   // 8 MB [BH,4,64,512]
    ushort_t* attn = (ushort_t*)(ws + ((size_t)40 << 20));   // 8 MB

    cast_all<<<8192, 256, 0, stream>>>(x, Wq, Wk, Wv, Wo, xbf, wqkv, wob);

    gemm_qkv<<<dim3(32, 24), 256, 0, stream>>>(xbf, wqkv, bq, bk, bv,
                                               Qb, Kss, Vts);

    sparse_attn9<<<dim3(1024), 256, 0, stream>>>(Qb, Kss, Vts, attn);

    gemm_o<<<dim3(64, 8), 256, 0, stream>>>(attn, wob, bo, (float*)d_out);
}